// Round 14
// baseline (3504.131 us; speedup 1.0000x reference)
//
#include <hip/hip_runtime.h>
#include <cstdint>
#include <cstddef>

#define NEGV -1.0e9f
#define NB 4              // row-blocks per batch
#define BW 4              // waves per row-block

// Branchless logaddexp, bit-identical to the verified branch form.
__device__ __forceinline__ float lse_f(float a, float b) {
    float d = a - b;
    float m = fmaxf(a, b);
    return m + log1pf(expf(-fabsf(d)));
}

// Packed anti-diagonal geometry for the bundle buffer.
__device__ __forceinline__ void diag_geo(int d, int& st, int& L, int& tlo) {
    if (d < 64)        { st = (d * (d + 1)) >> 1;       L = d + 1;      tlo = 0; }
    else if (d < 1024) { st = 2080 + ((d - 64) << 6);   L = 64;         tlo = 0; }
    else               { int u = d - 1024;
                         st = 63520 + (u << 6) - ((u * (u + 1)) >> 1);
                         L = 63 - u;                    tlo = u + 1; }
}

// ---------------------------------------------------------------------------
// K1: T = emb @ W + b   (f64 accumulate), T: [22][512]
// ---------------------------------------------------------------------------
__global__ void k_embed(const float* __restrict__ emb, const float* __restrict__ W,
                        const float* __restrict__ b, double* __restrict__ T) {
    int idx = blockIdx.x * blockDim.x + threadIdx.x;
    if (idx >= 22 * 512) return;
    int a = idx >> 9, d = idx & 511;
    double acc = (double)b[d];
    const float* er = emb + a * 512;
    for (int k = 0; k < 512; ++k) acc += (double)er[k] * (double)W[k * 512 + d];
    T[idx] = acc;
}

// ---------------------------------------------------------------------------
// K2: G = T @ T^T (22x22), u1/u2 = T @ Wg halves, A[b] via index sums
// ---------------------------------------------------------------------------
__global__ void k_gau(const double* __restrict__ T, const int* __restrict__ x,
                      const int* __restrict__ y, const float* __restrict__ Wg,
                      const float* __restrict__ bg,
                      double* __restrict__ G, double* __restrict__ Aout) {
    __shared__ double u1s[22], u2s[22];
    int t = threadIdx.x;
    if (t < 484) {
        int a = t / 22, c = t % 22;
        const double* ra = T + a * 512;
        const double* rc = T + c * 512;
        double acc = 0.0;
        for (int d = 0; d < 512; ++d) acc += ra[d] * rc[d];
        G[t] = acc;
    }
    if (t < 22) {
        double acc = 0.0;
        const double* ra = T + t * 512;
        for (int d = 0; d < 512; ++d) acc += ra[d] * (double)Wg[d];
        u1s[t] = acc;
    } else if (t >= 64 && t < 86) {
        int a = t - 64;
        double acc = 0.0;
        const double* ra = T + a * 512;
        for (int d = 0; d < 512; ++d) acc += ra[d] * (double)Wg[512 + d];
        u2s[a] = acc;
    }
    __syncthreads();
    int w = t >> 6, lane = t & 63;
    const int* xb = x + w * 1024;
    const int* yb = y + w * 1024;
    double s = 0.0;
    for (int i = lane; i < 1024; i += 64) s += u1s[xb[i]] + u2s[yb[i]];
    for (int off = 32; off > 0; off >>= 1) s += __shfl_down(s, off);
    if (lane == 0) Aout[w] = s * (1.0 / 1024.0) + (double)bg[0];
}

// ---------------------------------------------------------------------------
// K3a: init V boundary (row 0 / col 0) + zero inter-block flags.
// ---------------------------------------------------------------------------
__global__ void k_vinit(float* __restrict__ Vbuf, int* __restrict__ gflag) {
    int b = blockIdx.x, t = threadIdx.x;
    float* Vb = Vbuf + (size_t)b * (1025 * 1025);
    Vb[t] = (t == 0) ? 0.0f : NEGV;                 // V[0][t]
    if (t == 0) Vb[1024] = NEGV;                    // V[0][1024]
    Vb[(size_t)(t + 1) * 1025] = NEGV;              // V[t+1][0]
    if (b == 0 && t < 64) gflag[t] = 0;
}

// ---------------------------------------------------------------------------
// K3b: split banded forward (r11-verbatim structure, 1 cell/lane/step) with
//      FUSED weight computation. The 4 weight expfs + 3 bundle stores depend
//      on inner/outer but nothing depends on them -> pure off-chain work that
//      fills the dependency-stall bubbles. Weight expressions verbatim from
//      the verified k_wb on bit-identical inputs -> bit-identical bundle.
// ---------------------------------------------------------------------------
__global__ __launch_bounds__(256) void k_fwds(const int* __restrict__ x,
                                              const int* __restrict__ y,
                                              const double* __restrict__ G,
                                              const double* __restrict__ Aarr,
                                              float* __restrict__ Vbuf,
                                              int* __restrict__ gflag,
                                              float* __restrict__ bw) {
    __shared__ float Gs[484];
    __shared__ int ys_s[1024];
    __shared__ float topbuf[BW][1024];   // topbuf[w][c] = V[256p + 64w][c+1]
    __shared__ int prog[BW];

    const int bid = blockIdx.x;
    const int b = bid & 7;               // batch (XCD-affine)
    const int p = bid >> 3;              // row-block 0..NB-1
    const int tid = threadIdx.x;         // 0..255
    const int w = tid >> 6;              // wave within block
    const int t = tid & 63;              // lane
    const int grow = (p << 8) + tid;     // global (row-1)
    float* Vb = Vbuf + (size_t)b * (1025 * 1025);

    for (int q = tid; q < 484; q += 256) Gs[q] = (float)G[q];
    for (int q = tid; q < 1024; q += 256) ys_s[q] = y[(b << 10) + q];
    if (tid < BW) prog[tid] = 0;
    const int xs = x[(b << 10) + grow];
    __syncthreads();

    const float A = (float)Aarr[b];
    const float* Grow = Gs + xs * 22;
    float* vst = Vb + (size_t)(grow + 1) * 1025 + 1;      // vst[j-1] = V[row][j]
    const float* tsrc = Vb + (size_t)(p << 8) * 1025;     // V[256p][*]
    float* bbp = bw + (size_t)b * 3145728;

    // per-lane bundle constants (row is fixed per lane)
    const int i_g = grow + 1;                              // global i
    const int rbU = (i_g - 2) >> 4, qU = (i_g - 2) & 15;   // wu/wd consumer row
    const int rbL = (i_g - 1) >> 4, qL = (i_g - 1) & 15;   // wl consumer row

    float vp = NEGV;                                      // V[row][j-1] carry
    float vdgc = (p == 0 && tid == 0) ? 0.0f : NEGV;      // V[row-1][j-1] carry
    float chunkv = NEGV;
    int cbase = 0;

    for (int s = 0; s < 1024 + 63; ++s) {
        // consumer blocks, wave 0: acquire + load producer chunk every 64 cols
        if (w == 0 && p > 0 && s < 1024 && (s & 63) == 0) {
            while (__hip_atomic_load(&gflag[(b << 2) + p - 1], __ATOMIC_ACQUIRE,
                                     __HIP_MEMORY_SCOPE_AGENT) < s + 64)
                __builtin_amdgcn_s_sleep(2);
            chunkv = tsrc[s + 1 + t];     // V[256p][s+1..s+64], bit-exact
            cbase = s;
        }
        // waves >0: internal LDS group-sync every 16 cols
        if (w > 0 && s < 1024 && (s & 15) == 0) {
            const int target = (s + 16 < 1024) ? s + 16 : 1024;
            while (__hip_atomic_load(&prog[w], __ATOMIC_ACQUIRE,
                                     __HIP_MEMORY_SCOPE_WORKGROUP) < target)
                __builtin_amdgcn_s_sleep(1);
        }
        float vu_l0;
        if (w == 0)
            vu_l0 = (p == 0) ? NEGV : __shfl(chunkv, s - cbase);
        else
            vu_l0 = topbuf[w][(s < 1024) ? s : 1023];
        const float ush = __shfl_up(vp, 1);   // lane t-1's v at col j
        const int j = s - t + 1;
        if (j >= 1 && j <= 1024) {
            float vu = (t == 0) ? vu_l0 : ush;
            // ---- cell math (verbatim bit-identical sequence) ----
            float t1 = vu + A;
            float t2 = vp + A;
            float inner = lse_f(t1, vdgc);
            float outer = lse_f(inner, t2);
            float v = Grow[ys_s[j - 1]] + outer;
            vst[j - 1] = v;                   // global store stays in flight
            // ---- fused weights (off the dependency chain) ----
            float go1 = expf(inner - outer);
            float wlW = expf(t2 - outer);
            float wuW = go1 * expf(t1 - inner);
            float wdW = go1 * expf(vdgc - inner);
            if (i_g >= 2) {
                int st, L, tlo;
                diag_geo(rbU + (j - 1), st, L, tlo);     // wu -> consumer (i-1, j)
                int f = 3 * qU;
                bbp[(size_t)st * 48 + (size_t)(f >> 2) * 4 * L
                    + ((rbU - tlo) << 2) + (f & 3)] = wuW;
                if (j >= 2) {
                    diag_geo(rbU + (j - 2), st, L, tlo); // wd -> consumer (i-1, j-1)
                    f = 3 * qU + 1;
                    bbp[(size_t)st * 48 + (size_t)(f >> 2) * 4 * L
                        + ((rbU - tlo) << 2) + (f & 3)] = wdW;
                }
            }
            if (j >= 2) {
                int st, L, tlo;
                diag_geo(rbL + (j - 2), st, L, tlo);     // wl -> consumer (i, j-1)
                int f = 3 * qL + 2;
                bbp[(size_t)st * 48 + (size_t)(f >> 2) * 4 * L
                    + ((rbL - tlo) << 2) + (f & 3)] = wlW;
            }
            // ---- handoff (verbatim r11) ----
            if (t == 63) {
                if (w < BW - 1) {
                    topbuf[w + 1][j - 1] = v;
                    if ((j & 15) == 0)
                        __hip_atomic_store(&prog[w + 1], j, __ATOMIC_RELEASE,
                                           __HIP_MEMORY_SCOPE_WORKGROUP);
                } else if (p < NB - 1) {
                    if ((j & 63) == 0) {
                        __threadfence();
                        __hip_atomic_store(&gflag[(b << 2) + p], j,
                                           __ATOMIC_RELEASE, __HIP_MEMORY_SCOPE_AGENT);
                    }
                }
            }
            vp = v; vdgc = vu;
        }
    }
}

// ---------------------------------------------------------------------------
// K5: single-launch backward, packed-diagonal coalesced bundle reads.
//     (verbatim from the verified round-9 kernel; bit-identical E order)
// ---------------------------------------------------------------------------
__global__ __launch_bounds__(64) void k_bwd16(const float* __restrict__ bw,
                                              float* __restrict__ out) {
    const int t = threadIdx.x;
    const int b = blockIdx.x;
    const float* bb = bw + (size_t)b * 3145728;
    float* ob = out + ((size_t)b << 20);
    const int r0 = t << 4;              // (i-1) base = 16t

    float e[16];
    float4 cwv[12], pfv[12];
    #pragma unroll
    for (int q = 0; q < 16; ++q) e[q] = 0.f;

    {
        int st, L, tlo; diag_geo(t + 1023, st, L, tlo);
        const float* base = bb + (size_t)st * 48;
        #pragma unroll
        for (int k = 0; k < 12; ++k)
            cwv[k] = *(const float4*)(base + (size_t)k * 4 * L);
    }

    float sdb = 0.f;
    for (int s = 0; s < 1087; ++s) {
        float dn = __shfl_down(e[0], 1);    // lane t+1's top value at col cj
        const int d = 1086 - s;
        const int cj = d - t;               // this lane's column (j-1)
        if (cj >= 0 && cj < 1024) {
            {
                int st, L, tlo; diag_geo(d - 1, st, L, tlo);
                const int p = t - tlo;
                const float* base = bb + (size_t)st * 48 + ((size_t)p << 2);
                #pragma unroll
                for (int k = 0; k < 12; ++k)
                    pfv[k] = *(const float4*)(base + (size_t)k * 4 * L);
            }
            const float* F = (const float*)cwv;

            float old_b = e[15];
            float eu = (t == 63) ? 0.f : dn;
            float ed = (t == 63) ? 0.f : sdb;
            float v = eu * F[45] + ed * F[46] + old_b * F[47];
            if (t == 63 && cj == 1023) v = 1.0f;    // seed E[1024][1024] = 1
            e[15] = v;
            float new_b = v;
            #pragma unroll
            for (int q = 14; q >= 0; --q) {
                float oq = e[q];
                v = new_b * F[3 * q] + old_b * F[3 * q + 1] + oq * F[3 * q + 2];
                e[q] = v;
                new_b = v; old_b = oq;
            }
            #pragma unroll
            for (int k = 0; k < 4; ++k)
                *(float4*)&ob[(size_t)cj * 1024 + r0 + 4 * k] =
                    make_float4(e[4*k], e[4*k+1], e[4*k+2], e[4*k+3]);
            #pragma unroll
            for (int k = 0; k < 12; ++k) cwv[k] = pfv[k];
        }
        sdb = dn;
    }
}

// ---------------------------------------------------------------------------
// Fallback: round-2 monolithic forward+backward (used only if ws too small).
// ---------------------------------------------------------------------------
template <bool FAITHFUL>
__global__ __launch_bounds__(1024) void k_dp(const int* __restrict__ x,
                                             const int* __restrict__ y,
                                             const double* __restrict__ G,
                                             const double* __restrict__ Aarr,
                                             float2* __restrict__ wbuf,
                                             float* __restrict__ wdbuf,
                                             float* __restrict__ out) {
    __shared__ float Gs[484];
    __shared__ int xs[1024], ys[1024];
    __shared__ float D[3][1025];
    __shared__ float E[3][1026];

    const int b = blockIdx.x;
    const int t = threadIdx.x;
    const int i = t + 1;

    if (t < 484) Gs[t] = (float)G[t];
    xs[t] = x[(b << 10) + t];
    ys[t] = y[(b << 10) + t];
    D[0][t + 1] = NEGV;
    D[1][t + 1] = NEGV;
    E[0][t] = 0.f; E[1][t] = 0.f; E[2][t] = 0.f;
    if (t == 0) {
        D[0][0] = 0.0f;
        D[1][0] = NEGV;
        E[0][1024] = 0.f; E[0][1025] = 0.f;
        E[1][1024] = 0.f; E[1][1025] = 0.f;
        E[2][1024] = 0.f; E[2][1025] = 0.f;
    }
    __syncthreads();

    const float A = (float)Aarr[b];
    const float* Grow = Gs + xs[t] * 22;
    float2* wb = wbuf + ((size_t)b << 20);
    float*  wdb = wdbuf + ((size_t)b << 20);

    for (int k = 2; k <= 2048; ++k) {
        const int cur = k % 3, p1 = (k + 2) % 3, p2 = (k + 1) % 3;
        const int j = k - i;
        if (j >= 1 && j <= 1024) {
            float vu  = D[p1][i - 1];
            float vdg = D[p2][i - 1];
            float vl  = D[p1][i];
            float t1 = vu + A;
            float t2 = vl + A;
            float di = t1 - vdg;
            float inner = (di > 0.f) ? (t1  + log1pf(expf(-di)))
                                     : (vdg + log1pf(expf(di)));
            float dw = inner - t2;
            float outer = (dw > 0.f) ? (inner + log1pf(expf(-dw)))
                                     : (t2    + log1pf(expf(dw)));
            D[cur][i] = Grow[ys[j - 1]] + outer;
            float go1 = expf(inner - outer);
            float wlW = expf(t2 - outer);
            float wuW = go1 * expf(t1 - inner);
            size_t ci = ((size_t)t << 10) + (j - 1);
            wb[ci] = make_float2(wuW, wlW);
            if (FAITHFUL) wdb[ci] = go1 * expf(vdg - inner);
        }
        if (t == 0) D[cur][0] = NEGV;
        if (i == k && k <= 1024) D[cur][k] = NEGV;
        __syncthreads();
    }

    __syncthreads();

    float* ob = out + ((size_t)b << 20);

    for (int k = 2048; k >= 2; --k) {
        const int cur = k % 3, n1 = (k + 1) % 3, n2 = (k + 2) % 3;
        const int j = k - i;
        if (j >= 1 && j <= 1024) {
            float e;
            if (k == 2048) {
                e = 1.0f;
            } else {
                float Eu = E[n1][i + 1];
                float Ed = E[n2][i + 1];
                float El = E[n1][i];
                int iw = (i < 1024) ? i : 1023;
                int jw = (j < 1024) ? j : 1023;
                float2 w_up = wb[((size_t)iw << 10) + (j - 1)];
                float2 w_lf = wb[((size_t)(i - 1) << 10) + jw];
                float w_dd;
                if (FAITHFUL) {
                    w_dd = wdb[((size_t)iw << 10) + jw];
                } else {
                    float2 w_dg = wb[((size_t)iw << 10) + jw];
                    w_dd = 1.0f - w_dg.x - w_dg.y;
                }
                e = Eu * w_up.x + Ed * w_dd + El * w_lf.y;
            }
            E[cur][i] = e;
            ob[((size_t)(j - 1) << 10) + (i - 1)] = e;
        } else {
            E[cur][i] = 0.f;
        }
        __syncthreads();
    }
}

// ---------------------------------------------------------------------------
extern "C" void kernel_launch(void* const* d_in, const int* in_sizes, int n_in,
                              void* d_out, int out_size, void* d_ws, size_t ws_size,
                              hipStream_t stream) {
    const int*   x   = (const int*)d_in[0];
    const int*   y   = (const int*)d_in[1];
    const float* emb = (const float*)d_in[2];
    const float* W   = (const float*)d_in[3];
    const float* b   = (const float*)d_in[4];
    const float* Wg  = (const float*)d_in[5];
    const float* bg  = (const float*)d_in[6];
    float* out = (float*)d_out;

    char* ws = (char*)d_ws;
    double* T    = (double*)(ws + 0);                       // 90112 B
    double* G    = (double*)(ws + 90112);                   // 3872 B
    double* Aarr = (double*)(ws + 94336);                   // 64 B
    float*  bund = (float*)(ws + 131072);                   // 96 MiB (packed diagonals)
    float2* wbuf = (float2*)(ws + 131072);                  // (fallback layout)
    float*  wdbuf = (float*)(ws + 131072 + ((size_t)64 << 20));
    float*  Vbuf = (float*)(ws + 131072 + ((size_t)96 << 20));   // 33.6 MB
    int*    gflag = (int*)(ws + 131072 + ((size_t)96 << 20) + (size_t)8 * 1025 * 1025 * 4);

    k_embed<<<44, 256, 0, stream>>>(emb, W, b, T);
    k_gau<<<1, 512, 0, stream>>>(T, x, y, Wg, bg, G, Aarr);

    const size_t need_old = 131072 + ((size_t)96 << 20);
    const size_t need_new = need_old + (size_t)8 * 1025 * 1025 * 4 + 4096;

    if (ws_size >= need_new) {
        k_vinit<<<8, 1024, 0, stream>>>(Vbuf, gflag);
        k_fwds<<<8 * NB, 256, 0, stream>>>(x, y, G, Aarr, Vbuf, gflag, bund);
        k_bwd16<<<8, 64, 0, stream>>>(bund, out);
    } else if (ws_size >= need_old) {
        k_dp<true><<<8, 1024, 0, stream>>>(x, y, G, Aarr, wbuf, wdbuf, out);
    } else {
        k_dp<false><<<8, 1024, 0, stream>>>(x, y, G, Aarr, wbuf, wdbuf, out);
    }
}

// Round 15
// 2626.062 us; speedup vs baseline: 1.3344x; 1.3344x over previous
//
#include <hip/hip_runtime.h>
#include <cstdint>
#include <cstddef>

#define NEGV -1.0e9f
#define NB 4              // row-blocks per batch
#define BW 4              // waves per row-block

// Branchless logaddexp, bit-identical to the verified branch form.
__device__ __forceinline__ float lse_f(float a, float b) {
    float d = a - b;
    float m = fmaxf(a, b);
    return m + log1pf(expf(-fabsf(d)));
}
__device__ __forceinline__ float cellfwd(float th, float vu, float vdg, float vl, float A) {
    float inner = lse_f(vu + A, vdg);
    float outer = lse_f(inner, vl + A);
    return th + outer;
}

// Packed anti-diagonal geometry for the bundle buffer.
__device__ __forceinline__ void diag_geo(int d, int& st, int& L, int& tlo) {
    if (d < 64)        { st = (d * (d + 1)) >> 1;       L = d + 1;      tlo = 0; }
    else if (d < 1024) { st = 2080 + ((d - 64) << 6);   L = 64;         tlo = 0; }
    else               { int u = d - 1024;
                         st = 63520 + (u << 6) - ((u * (u + 1)) >> 1);
                         L = 63 - u;                    tlo = u + 1; }
}

// ---------------------------------------------------------------------------
// K1: T = emb @ W + b   (f64 accumulate), T: [22][512]
// ---------------------------------------------------------------------------
__global__ void k_embed(const float* __restrict__ emb, const float* __restrict__ W,
                        const float* __restrict__ b, double* __restrict__ T) {
    int idx = blockIdx.x * blockDim.x + threadIdx.x;
    if (idx >= 22 * 512) return;
    int a = idx >> 9, d = idx & 511;
    double acc = (double)b[d];
    const float* er = emb + a * 512;
    for (int k = 0; k < 512; ++k) acc += (double)er[k] * (double)W[k * 512 + d];
    T[idx] = acc;
}

// ---------------------------------------------------------------------------
// K2: G = T @ T^T (22x22), u1/u2 = T @ Wg halves, A[b] via index sums
// ---------------------------------------------------------------------------
__global__ void k_gau(const double* __restrict__ T, const int* __restrict__ x,
                      const int* __restrict__ y, const float* __restrict__ Wg,
                      const float* __restrict__ bg,
                      double* __restrict__ G, double* __restrict__ Aout) {
    __shared__ double u1s[22], u2s[22];
    int t = threadIdx.x;
    if (t < 484) {
        int a = t / 22, c = t % 22;
        const double* ra = T + a * 512;
        const double* rc = T + c * 512;
        double acc = 0.0;
        for (int d = 0; d < 512; ++d) acc += ra[d] * rc[d];
        G[t] = acc;
    }
    if (t < 22) {
        double acc = 0.0;
        const double* ra = T + t * 512;
        for (int d = 0; d < 512; ++d) acc += ra[d] * (double)Wg[d];
        u1s[t] = acc;
    } else if (t >= 64 && t < 86) {
        int a = t - 64;
        double acc = 0.0;
        const double* ra = T + a * 512;
        for (int d = 0; d < 512; ++d) acc += ra[d] * (double)Wg[512 + d];
        u2s[a] = acc;
    }
    __syncthreads();
    int w = t >> 6, lane = t & 63;
    const int* xb = x + w * 1024;
    const int* yb = y + w * 1024;
    double s = 0.0;
    for (int i = lane; i < 1024; i += 64) s += u1s[xb[i]] + u2s[yb[i]];
    for (int off = 32; off > 0; off >>= 1) s += __shfl_down(s, off);
    if (lane == 0) Aout[w] = s * (1.0 / 1024.0) + (double)bg[0];
}

// ---------------------------------------------------------------------------
// K3a: init V boundary (row 0 / col 0) + zero inter-block flags.
// ---------------------------------------------------------------------------
__global__ void k_vinit(float* __restrict__ Vbuf, int* __restrict__ gflag) {
    int b = blockIdx.x, t = threadIdx.x;
    float* Vb = Vbuf + (size_t)b * (1025 * 1025);
    Vb[t] = (t == 0) ? 0.0f : NEGV;                 // V[0][t]
    if (t == 0) Vb[1024] = NEGV;                    // V[0][1024]
    Vb[(size_t)(t + 1) * 1025] = NEGV;              // V[t+1][0]
    if (b == 0 && t < 64) gflag[t] = 0;
}

// ---------------------------------------------------------------------------
// K3b: split banded forward (r11 structure). ONE change: the intra-block
//      16-col publish uses s_waitcnt lgkmcnt(0) + RELAXED flag store instead
//      of a WORKGROUP RELEASE atomic. The release fence was draining the
//      global scatter-store queue (vmcnt(0), ~900cy) onto the wave chain
//      every 16 steps; consumers only read LDS (topbuf), so lgkmcnt-only
//      ordering is sufficient: the data ds_writes are guaranteed in LDS
//      before the flag ds_write issues. Inter-block handoff (consumer reads
//      global V) keeps the full threadfence + AGENT release.
// ---------------------------------------------------------------------------
__global__ __launch_bounds__(256) void k_fwds(const int* __restrict__ x,
                                              const int* __restrict__ y,
                                              const double* __restrict__ G,
                                              const double* __restrict__ Aarr,
                                              float* __restrict__ Vbuf,
                                              int* __restrict__ gflag) {
    __shared__ float Gs[484];
    __shared__ int ys_s[1024];
    __shared__ float topbuf[BW][1024];   // topbuf[w][c] = V[256p + 64w][c+1]
    __shared__ int prog[BW];

    const int bid = blockIdx.x;
    const int b = bid & 7;               // batch (XCD-affine)
    const int p = bid >> 3;              // row-block 0..NB-1
    const int tid = threadIdx.x;         // 0..255
    const int w = tid >> 6;              // wave within block
    const int t = tid & 63;              // lane
    const int grow = (p << 8) + tid;     // global (row-1)
    float* Vb = Vbuf + (size_t)b * (1025 * 1025);

    for (int q = tid; q < 484; q += 256) Gs[q] = (float)G[q];
    for (int q = tid; q < 1024; q += 256) ys_s[q] = y[(b << 10) + q];
    if (tid < BW) prog[tid] = 0;
    const int xs = x[(b << 10) + grow];
    __syncthreads();

    const float A = (float)Aarr[b];
    const float* Grow = Gs + xs * 22;
    float* vst = Vb + (size_t)(grow + 1) * 1025 + 1;      // vst[j-1] = V[row][j]
    const float* tsrc = Vb + (size_t)(p << 8) * 1025;     // V[256p][*]

    float vp = NEGV;                                      // V[row][j-1] carry
    float vdgc = (p == 0 && tid == 0) ? 0.0f : NEGV;      // V[row-1][j-1] carry seed
    float chunkv = NEGV;
    int cbase = 0;

    for (int s = 0; s < 1024 + 63; ++s) {
        // consumer blocks, wave 0: acquire + load producer chunk every 64 cols
        if (w == 0 && p > 0 && s < 1024 && (s & 63) == 0) {
            while (__hip_atomic_load(&gflag[(b << 2) + p - 1], __ATOMIC_ACQUIRE,
                                     __HIP_MEMORY_SCOPE_AGENT) < s + 64)
                __builtin_amdgcn_s_sleep(2);
            chunkv = tsrc[s + 1 + t];     // V[256p][s+1..s+64], bit-exact from global
            cbase = s;
        }
        // waves >0: internal LDS group-sync every 16 cols (RELAXED spin; the
        // flag ds_write is ordered after data by the producer's lgkmcnt wait)
        if (w > 0 && s < 1024 && (s & 15) == 0) {
            const int target = (s + 16 < 1024) ? s + 16 : 1024;
            while (__hip_atomic_load(&prog[w], __ATOMIC_RELAXED,
                                     __HIP_MEMORY_SCOPE_WORKGROUP) < target)
                __builtin_amdgcn_s_sleep(1);
            asm volatile("" ::: "memory");   // keep topbuf reads after the spin
        }
        float vu_l0;
        if (w == 0)
            vu_l0 = (p == 0) ? NEGV : __shfl(chunkv, s - cbase);
        else
            vu_l0 = topbuf[w][(s < 1024) ? s : 1023];
        const float ush = __shfl_up(vp, 1);   // lane t-1's v at col j
        const int j = s - t + 1;
        if (j >= 1 && j <= 1024) {
            float vu = (t == 0) ? vu_l0 : ush;
            float v = cellfwd(Grow[ys_s[j - 1]], vu, vdgc, vp, A);
            vst[j - 1] = v;                   // global store stays in flight
            if (t == 63) {
                if (w < BW - 1) {
                    topbuf[w + 1][j - 1] = v; // hand bottom row to next wave
                    if ((j & 15) == 0) {
                        // lgkmcnt-only publish: data ds_writes complete, then flag
                        asm volatile("s_waitcnt lgkmcnt(0)" ::: "memory");
                        __hip_atomic_store(&prog[w + 1], j, __ATOMIC_RELAXED,
                                           __HIP_MEMORY_SCOPE_WORKGROUP);
                    }
                } else if (p < NB - 1) {
                    if ((j & 63) == 0) {      // publish chunk to next block
                        __threadfence();
                        __hip_atomic_store(&gflag[(b << 2) + p], j,
                                           __ATOMIC_RELEASE, __HIP_MEMORY_SCOPE_AGENT);
                    }
                }
            }
            vp = v; vdgc = vu;
        }
    }
}

// ---------------------------------------------------------------------------
// K4: weight kernel — recompute each cell's softmax weights (bit-identical
//     inputs from stored V), scatter into the packed-diagonal bundle layout.
// ---------------------------------------------------------------------------
__global__ __launch_bounds__(256) void k_wb(const double* __restrict__ Aarr,
                                            const float* __restrict__ Vbuf,
                                            float* __restrict__ bw) {
    int idx = blockIdx.x * 256 + threadIdx.x;
    int b = idx >> 20;
    int cell = idx & 1048575;
    int i = (cell >> 10) + 1;        // 1..1024
    int j = (cell & 1023) + 1;       // 1..1024
    const float* Vb = Vbuf + (size_t)b * (1025 * 1025);
    float vu  = Vb[(size_t)(i - 1) * 1025 + j];
    float vdg = Vb[(size_t)(i - 1) * 1025 + (j - 1)];
    float vl  = Vb[(size_t)i * 1025 + (j - 1)];
    float A = (float)Aarr[b];
    float t1 = vu + A;
    float t2 = vl + A;
    float di = t1 - vdg;
    float inner = (di > 0.f) ? (t1  + log1pf(expf(-di)))
                             : (vdg + log1pf(expf(di)));
    float dw = inner - t2;
    float outer = (dw > 0.f) ? (inner + log1pf(expf(-dw)))
                             : (t2    + log1pf(expf(dw)));
    float go1 = expf(inner - outer);
    float wlW = expf(t2 - outer);
    float wuW = go1 * expf(t1 - inner);
    float wdW = go1 * expf(vdg - inner);
    float* bbp = bw + (size_t)b * 3145728;

    if (i >= 2) {        // wu -> consumer (i-1, j)
        int rb = (i - 2) >> 4, q = (i - 2) & 15, cj = j - 1;
        int st, L, tlo; diag_geo(rb + cj, st, L, tlo);
        int f = 3 * q;
        bbp[(size_t)st * 48 + (size_t)(f >> 2) * 4 * L + ((rb - tlo) << 2) + (f & 3)] = wuW;
    }
    if (i >= 2 && j >= 2) {   // wd -> consumer (i-1, j-1)
        int rb = (i - 2) >> 4, q = (i - 2) & 15, cj = j - 2;
        int st, L, tlo; diag_geo(rb + cj, st, L, tlo);
        int f = 3 * q + 1;
        bbp[(size_t)st * 48 + (size_t)(f >> 2) * 4 * L + ((rb - tlo) << 2) + (f & 3)] = wdW;
    }
    if (j >= 2) {        // wl -> consumer (i, j-1)
        int rb = (i - 1) >> 4, q = (i - 1) & 15, cj = j - 2;
        int st, L, tlo; diag_geo(rb + cj, st, L, tlo);
        int f = 3 * q + 2;
        bbp[(size_t)st * 48 + (size_t)(f >> 2) * 4 * L + ((rb - tlo) << 2) + (f & 3)] = wlW;
    }
}

// ---------------------------------------------------------------------------
// K5: single-launch backward, packed-diagonal coalesced bundle reads.
//     (verbatim from the verified round-9 kernel; bit-identical E order)
// ---------------------------------------------------------------------------
__global__ __launch_bounds__(64) void k_bwd16(const float* __restrict__ bw,
                                              float* __restrict__ out) {
    const int t = threadIdx.x;
    const int b = blockIdx.x;
    const float* bb = bw + (size_t)b * 3145728;
    float* ob = out + ((size_t)b << 20);
    const int r0 = t << 4;              // (i-1) base = 16t

    float e[16];
    float4 cwv[12], pfv[12];
    #pragma unroll
    for (int q = 0; q < 16; ++q) e[q] = 0.f;

    {
        int st, L, tlo; diag_geo(t + 1023, st, L, tlo);
        const float* base = bb + (size_t)st * 48;
        #pragma unroll
        for (int k = 0; k < 12; ++k)
            cwv[k] = *(const float4*)(base + (size_t)k * 4 * L);
    }

    float sdb = 0.f;
    for (int s = 0; s < 1087; ++s) {
        float dn = __shfl_down(e[0], 1);    // lane t+1's top value at col cj
        const int d = 1086 - s;
        const int cj = d - t;               // this lane's column (j-1)
        if (cj >= 0 && cj < 1024) {
            {
                int st, L, tlo; diag_geo(d - 1, st, L, tlo);
                const int p = t - tlo;
                const float* base = bb + (size_t)st * 48 + ((size_t)p << 2);
                #pragma unroll
                for (int k = 0; k < 12; ++k)
                    pfv[k] = *(const float4*)(base + (size_t)k * 4 * L);
            }
            const float* F = (const float*)cwv;

            float old_b = e[15];
            float eu = (t == 63) ? 0.f : dn;
            float ed = (t == 63) ? 0.f : sdb;
            float v = eu * F[45] + ed * F[46] + old_b * F[47];
            if (t == 63 && cj == 1023) v = 1.0f;    // seed E[1024][1024] = 1
            e[15] = v;
            float new_b = v;
            #pragma unroll
            for (int q = 14; q >= 0; --q) {
                float oq = e[q];
                v = new_b * F[3 * q] + old_b * F[3 * q + 1] + oq * F[3 * q + 2];
                e[q] = v;
                new_b = v; old_b = oq;
            }
            #pragma unroll
            for (int k = 0; k < 4; ++k)
                *(float4*)&ob[(size_t)cj * 1024 + r0 + 4 * k] =
                    make_float4(e[4*k], e[4*k+1], e[4*k+2], e[4*k+3]);
            #pragma unroll
            for (int k = 0; k < 12; ++k) cwv[k] = pfv[k];
        }
        sdb = dn;
    }
}

// ---------------------------------------------------------------------------
// Fallback: round-2 monolithic forward+backward (used only if ws too small).
// ---------------------------------------------------------------------------
template <bool FAITHFUL>
__global__ __launch_bounds__(1024) void k_dp(const int* __restrict__ x,
                                             const int* __restrict__ y,
                                             const double* __restrict__ G,
                                             const double* __restrict__ Aarr,
                                             float2* __restrict__ wbuf,
                                             float* __restrict__ wdbuf,
                                             float* __restrict__ out) {
    __shared__ float Gs[484];
    __shared__ int xs[1024], ys[1024];
    __shared__ float D[3][1025];
    __shared__ float E[3][1026];

    const int b = blockIdx.x;
    const int t = threadIdx.x;
    const int i = t + 1;

    if (t < 484) Gs[t] = (float)G[t];
    xs[t] = x[(b << 10) + t];
    ys[t] = y[(b << 10) + t];
    D[0][t + 1] = NEGV;
    D[1][t + 1] = NEGV;
    E[0][t] = 0.f; E[1][t] = 0.f; E[2][t] = 0.f;
    if (t == 0) {
        D[0][0] = 0.0f;
        D[1][0] = NEGV;
        E[0][1024] = 0.f; E[0][1025] = 0.f;
        E[1][1024] = 0.f; E[1][1025] = 0.f;
        E[2][1024] = 0.f; E[2][1025] = 0.f;
    }
    __syncthreads();

    const float A = (float)Aarr[b];
    const float* Grow = Gs + xs[t] * 22;
    float2* wb = wbuf + ((size_t)b << 20);
    float*  wdb = wdbuf + ((size_t)b << 20);

    for (int k = 2; k <= 2048; ++k) {
        const int cur = k % 3, p1 = (k + 2) % 3, p2 = (k + 1) % 3;
        const int j = k - i;
        if (j >= 1 && j <= 1024) {
            float vu  = D[p1][i - 1];
            float vdg = D[p2][i - 1];
            float vl  = D[p1][i];
            float t1 = vu + A;
            float t2 = vl + A;
            float di = t1 - vdg;
            float inner = (di > 0.f) ? (t1  + log1pf(expf(-di)))
                                     : (vdg + log1pf(expf(di)));
            float dw = inner - t2;
            float outer = (dw > 0.f) ? (inner + log1pf(expf(-dw)))
                                     : (t2    + log1pf(expf(dw)));
            D[cur][i] = Grow[ys[j - 1]] + outer;
            float go1 = expf(inner - outer);
            float wlW = expf(t2 - outer);
            float wuW = go1 * expf(t1 - inner);
            size_t ci = ((size_t)t << 10) + (j - 1);
            wb[ci] = make_float2(wuW, wlW);
            if (FAITHFUL) wdb[ci] = go1 * expf(vdg - inner);
        }
        if (t == 0) D[cur][0] = NEGV;
        if (i == k && k <= 1024) D[cur][k] = NEGV;
        __syncthreads();
    }

    __syncthreads();

    float* ob = out + ((size_t)b << 20);

    for (int k = 2048; k >= 2; --k) {
        const int cur = k % 3, n1 = (k + 1) % 3, n2 = (k + 2) % 3;
        const int j = k - i;
        if (j >= 1 && j <= 1024) {
            float e;
            if (k == 2048) {
                e = 1.0f;
            } else {
                float Eu = E[n1][i + 1];
                float Ed = E[n2][i + 1];
                float El = E[n1][i];
                int iw = (i < 1024) ? i : 1023;
                int jw = (j < 1024) ? j : 1023;
                float2 w_up = wb[((size_t)iw << 10) + (j - 1)];
                float2 w_lf = wb[((size_t)(i - 1) << 10) + jw];
                float w_dd;
                if (FAITHFUL) {
                    w_dd = wdb[((size_t)iw << 10) + jw];
                } else {
                    float2 w_dg = wb[((size_t)iw << 10) + jw];
                    w_dd = 1.0f - w_dg.x - w_dg.y;
                }
                e = Eu * w_up.x + Ed * w_dd + El * w_lf.y;
            }
            E[cur][i] = e;
            ob[((size_t)(j - 1) << 10) + (i - 1)] = e;
        } else {
            E[cur][i] = 0.f;
        }
        __syncthreads();
    }
}

// ---------------------------------------------------------------------------
extern "C" void kernel_launch(void* const* d_in, const int* in_sizes, int n_in,
                              void* d_out, int out_size, void* d_ws, size_t ws_size,
                              hipStream_t stream) {
    const int*   x   = (const int*)d_in[0];
    const int*   y   = (const int*)d_in[1];
    const float* emb = (const float*)d_in[2];
    const float* W   = (const float*)d_in[3];
    const float* b   = (const float*)d_in[4];
    const float* Wg  = (const float*)d_in[5];
    const float* bg  = (const float*)d_in[6];
    float* out = (float*)d_out;

    char* ws = (char*)d_ws;
    double* T    = (double*)(ws + 0);                       // 90112 B
    double* G    = (double*)(ws + 90112);                   // 3872 B
    double* Aarr = (double*)(ws + 94336);                   // 64 B
    float*  bund = (float*)(ws + 131072);                   // 96 MiB (packed diagonals)
    float2* wbuf = (float2*)(ws + 131072);                  // (fallback layout)
    float*  wdbuf = (float*)(ws + 131072 + ((size_t)64 << 20));
    float*  Vbuf = (float*)(ws + 131072 + ((size_t)96 << 20));   // 33.6 MB
    int*    gflag = (int*)(ws + 131072 + ((size_t)96 << 20) + (size_t)8 * 1025 * 1025 * 4);

    k_embed<<<44, 256, 0, stream>>>(emb, W, b, T);
    k_gau<<<1, 512, 0, stream>>>(T, x, y, Wg, bg, G, Aarr);

    const size_t need_old = 131072 + ((size_t)96 << 20);
    const size_t need_new = need_old + (size_t)8 * 1025 * 1025 * 4 + 4096;

    if (ws_size >= need_new) {
        k_vinit<<<8, 1024, 0, stream>>>(Vbuf, gflag);
        k_fwds<<<8 * NB, 256, 0, stream>>>(x, y, G, Aarr, Vbuf, gflag);
        k_wb<<<8 * 1024 * 1024 / 256, 256, 0, stream>>>(Aarr, Vbuf, bund);
        k_bwd16<<<8, 64, 0, stream>>>(bund, out);
    } else if (ws_size >= need_old) {
        k_dp<true><<<8, 1024, 0, stream>>>(x, y, G, Aarr, wbuf, wdbuf, out);
    } else {
        k_dp<false><<<8, 1024, 0, stream>>>(x, y, G, Aarr, wbuf, wdbuf, out);
    }
}